// Round 4
// baseline (266.629 us; speedup 1.0000x reference)
//
#include <hip/hip_runtime.h>
#include <math.h>

#define T 32
#define NEGS 0.1f
#define EPS 1e-5f
#define NREG 33

// ws layout (big path):
//   [0,1024): double accum[101]: [0]=sum_y [1]=sum_y2 [2..100]=hist S0/S1/S2
//   [1024, 1024+4k): float y[k]
//   [1024+4k, +16kT): float4 xg[T][k]
//   then float gPQ[2*NREG*32]
// fallback path: gPQ right after wsy.

__device__ __forceinline__ float rcp_fast(float x) { return __builtin_amdgcn_rcpf(x); }
__device__ __forceinline__ float sigm(float x) { return rcp_fast(1.0f + __expf(-x)); }
__device__ __forceinline__ float tanh_fast(float x) {
    float t = __expf(2.0f * fabsf(x));
    float r = 1.0f - 2.0f * rcp_fast(t + 1.0f);
    return copysignf(r, x);
}
__device__ __forceinline__ float lrelu(float x) { return x > 0.0f ? x : NEGS * x; }

__device__ __forceinline__ void bn1_params(const float* __restrict__ W1,
                                           const float* __restrict__ g1,
                                           const float* __restrict__ b1,
                                           const double* __restrict__ wsd, int k, int j,
                                           float& my, float& vy, float& a, float& b,
                                           float& tau, int& flip)
{
    my = (float)(wsd[0] / k);
    vy = (float)(wsd[1] / k) - my * my;
    float wj = W1[j];
    a = g1[j] * wj * rsqrtf(fmaf(wj * wj, vy, EPS));
    b = b1[j];
    if (a > 0.0f)      { tau = my - b / a; flip = 0; }
    else if (a < 0.0f) { tau = my - b / a; flip = 1; }
    else               { tau = (b > 0.0f ? -__builtin_inff() : __builtin_inff()); flip = 0; }
}

// ---------------- Kernel A: gate precompute --------------------------------
// PERSISTENT grid-stride blocks + register prefetch (async-STAGE split).
// One-shot blocks stall wholesale at the vmcnt(0)+barrier, so the memory
// pipe is fed in bursts (~3 TB/s delivered). Here each block loops over
// groups of 8 samples; the NEXT group's 25.6 KB is issued into registers
// BEFORE the barrier, so HBM latency hides under the current group's
// LDS compute + store. 1536 blocks = 6/CU (LDS 26112 B).
__global__ __launch_bounds__(256)
void gates_kernel(const float* __restrict__ r, const float* __restrict__ v,
                  const float* __restrict__ u, const float* __restrict__ wih0,
                  float4* __restrict__ xg, int k, int ngroups)
{
    __shared__ float rbuf[8 * 32 * 9];   // 2304 floats
    __shared__ float vbuf[8 * 32 * 6];   // 1536 floats
    __shared__ float ubuf[8 * 32 * 6];   // 1536 floats
    __shared__ float obuf[32 * 36];      // output transpose staging
    const int tid = threadIdx.x;

    float4* rb4 = reinterpret_cast<float4*>(rbuf);
    float4* vb4 = reinterpret_cast<float4*>(vbuf);
    float4* ub4 = reinterpret_cast<float4*>(ubuf);

    // weights are wave-uniform -> scalar regs
    float wi0[4][21];
#pragma unroll
    for (int g = 0; g < 4; ++g)
#pragma unroll
        for (int j = 0; j < 21; ++j) wi0[g][j] = wih0[g * 21 + j];

    // prefetch registers for one group (28 VGPRs)
    float4 Ra0, Ra1, Ra2, Rv0, Rv1, Ru0, Ru1;

#define ISSUE_GROUP(gg)                                                         \
    do {                                                                        \
        const float4* r4_ = reinterpret_cast<const float4*>(r + (size_t)(gg) * (8 * T * 9)); \
        const float4* v4_ = reinterpret_cast<const float4*>(v + (size_t)(gg) * (8 * T * 6)); \
        const float4* u4_ = reinterpret_cast<const float4*>(u + (size_t)(gg) * (8 * T * 6)); \
        Ra0 = r4_[tid];                                                         \
        Ra1 = r4_[256 + tid];                                                   \
        if (tid < 64) Ra2 = r4_[512 + tid];                                     \
        Rv0 = v4_[tid];                                                         \
        if (tid < 128) Rv1 = v4_[256 + tid];                                    \
        Ru0 = u4_[tid];                                                         \
        if (tid < 128) Ru1 = u4_[256 + tid];                                    \
    } while (0)

    int g = blockIdx.x;
    const int gstride = gridDim.x;
    if (g >= ngroups) return;
    ISSUE_GROUP(g);

    while (g < ngroups) {
        // ---- commit prefetched regs to LDS (waits vmcnt for these regs) ----
        rb4[tid] = Ra0;
        rb4[256 + tid] = Ra1;
        if (tid < 64) rb4[512 + tid] = Ra2;
        vb4[tid] = Rv0;
        if (tid < 128) vb4[256 + tid] = Rv1;
        ub4[tid] = Ru0;
        if (tid < 128) ub4[256 + tid] = Ru1;

        // ---- issue NEXT group's loads; they fly during compute below ----
        const int gn = g + gstride;
        if (gn < ngroups) ISSUE_GROUP(gn);

        __syncthreads();   // staging buffers visible

        const int sl = tid >> 5, t = tid & 31;
        float x[21];
#pragma unroll
        for (int j = 0; j < 9; ++j) x[j] = rbuf[sl * (32 * 9) + t * 9 + j];
#pragma unroll
        for (int j = 0; j < 6; ++j) x[9 + j] = vbuf[sl * (32 * 6) + t * 6 + j];
#pragma unroll
        for (int j = 0; j < 6; ++j) x[15 + j] = ubuf[sl * (32 * 6) + t * 6 + j];

        float4 g4;
        float* gp = (float*)&g4;
#pragma unroll
        for (int gi = 0; gi < 4; ++gi) {
            float acc = 0.f;
#pragma unroll
            for (int j = 0; j < 21; ++j) acc = fmaf(wi0[gi][j], x[j], acc);
            gp[gi] = acc;
        }
        *(float4*)&obuf[t * 36 + sl * 4] = g4;
        __syncthreads();   // obuf ready; also fences LDS reads before next overwrite

        const int tG = tid >> 3, j = tid & 7;
        float4 val = *(const float4*)&obuf[tG * 36 + j * 4];
        xg[(size_t)tG * k + g * 8 + j] = val;

        g = gn;
    }
#undef ISSUE_GROUP
}

// ---------------- Kernel B: recurrence ---------------------------------------
// k = 65536 threads = 1024 waves on 1024 SIMDs -> structurally 1 wave/SIMD:
// NO TLP exists. Latency must be hidden by in-thread MLP. The asm memory
// clobber forces all 32 global_load_dwordx4 to issue BEFORE the recurrence
// (loads cannot sink past a potential store), paying the latency once.
__global__ __launch_bounds__(256, 1)
void recur_kernel(const float4* __restrict__ xg, const float* __restrict__ wihr,
                  const float* __restrict__ whhp, float* __restrict__ out,
                  double* __restrict__ wsd, float* __restrict__ wsy, int k)
{
    const int s = blockIdx.x * 256 + threadIdx.x;

    // issue ALL gate loads first: 32 loads in flight per thread
    float4 gbuf[T];
#pragma unroll
    for (int t = 0; t < T; ++t) gbuf[t] = xg[(size_t)t * k + s];

    float wir[4][4];
#pragma unroll
    for (int l = 0; l < 4; ++l)
#pragma unroll
        for (int g = 0; g < 4; ++g) wir[l][g] = wihr[l * 4 + g];
    float whh[5][4];
#pragma unroll
    for (int l = 0; l < 5; ++l)
#pragma unroll
        for (int g = 0; g < 4; ++g) whh[l][g] = whhp[l * 4 + g];

    // scheduling fence: no load may sink below this point
    asm volatile("" ::: "memory");

    float h[5] = {0.f, 0.f, 0.f, 0.f, 0.f};
    float c[5] = {0.f, 0.f, 0.f, 0.f, 0.f};
    float y0 = 0.f;

#pragma unroll
    for (int t = 0; t < T; ++t) {
        const float4 G = gbuf[t];
        float a0 = fmaf(whh[0][0], h[0], G.x);
        float a1 = fmaf(whh[0][1], h[0], G.y);
        float a2 = fmaf(whh[0][2], h[0], G.z);
        float a3 = fmaf(whh[0][3], h[0], G.w);
        {
            float ii = sigm(a0), ff = sigm(a1);
            float gg = tanh_fast(a2), oo = sigm(a3);
            c[0] = ff * c[0] + ii * gg;
            h[0] = oo * tanh_fast(c[0]);
        }
        float xin = h[0];
#pragma unroll
        for (int l = 1; l < 5; ++l) {
            float b0 = fmaf(wir[l - 1][0], xin, whh[l][0] * h[l]);
            float b1 = fmaf(wir[l - 1][1], xin, whh[l][1] * h[l]);
            float b2 = fmaf(wir[l - 1][2], xin, whh[l][2] * h[l]);
            float b3 = fmaf(wir[l - 1][3], xin, whh[l][3] * h[l]);
            float ii = sigm(b0), ff = sigm(b1);
            float gg = tanh_fast(b2), oo = sigm(b3);
            c[l] = ff * c[l] + ii * gg;
            h[l] = oo * tanh_fast(c[l]);
            xin = h[l];
        }
        if (t == 0) y0 = h[4];
    }

#pragma unroll
    for (int l = 0; l < 5; ++l) {
        out[(size_t)6 * k + (size_t)l * k + s] = h[l];
        out[(size_t)11 * k + (size_t)l * k + s] = c[l];
    }
    wsy[s] = y0;

    float ys = y0, yq = y0 * y0;
#pragma unroll
    for (int off = 32; off; off >>= 1) {
        ys += __shfl_down(ys, off);
        yq += __shfl_down(yq, off);
    }
    __shared__ float pS[4], pQ[4];
    const int wid = threadIdx.x >> 6, lane = threadIdx.x & 63;
    if (lane == 0) { pS[wid] = ys; pQ[wid] = yq; }
    __syncthreads();
    if (threadIdx.x == 0) {
        atomicAdd(&wsd[0], (double)(pS[0] + pS[1] + pS[2] + pS[3]));
        atomicAdd(&wsd[1], (double)(pQ[0] + pQ[1] + pQ[2] + pQ[3]));
    }
}

// ---------------- fallback fused LSTM (round-0 structure, known 98 us) --------
__global__ __launch_bounds__(256, 1)
void lstm_fused(const float* __restrict__ r, const float* __restrict__ v,
                const float* __restrict__ u,
                const float* __restrict__ wih0, const float* __restrict__ wihr,
                const float* __restrict__ whhp,
                float* __restrict__ out, double* __restrict__ wsd,
                float* __restrict__ wsy, int k)
{
    const int s = blockIdx.x * 256 + threadIdx.x;
    float wi0[4][21];
#pragma unroll
    for (int g = 0; g < 4; ++g)
#pragma unroll
        for (int j = 0; j < 21; ++j) wi0[g][j] = wih0[g * 21 + j];
    float wir[4][4];
#pragma unroll
    for (int l = 0; l < 4; ++l)
#pragma unroll
        for (int g = 0; g < 4; ++g) wir[l][g] = wihr[l * 4 + g];
    float whh[5][4];
#pragma unroll
    for (int l = 0; l < 5; ++l)
#pragma unroll
        for (int g = 0; g < 4; ++g) whh[l][g] = whhp[l * 4 + g];

    const float4* r4 = reinterpret_cast<const float4*>(r + (size_t)s * (T * 9));
    const float4* v4 = reinterpret_cast<const float4*>(v + (size_t)s * (T * 6));
    const float4* u4 = reinterpret_cast<const float4*>(u + (size_t)s * (T * 6));

    float h[5] = {0.f, 0.f, 0.f, 0.f, 0.f};
    float c[5] = {0.f, 0.f, 0.f, 0.f, 0.f};
    float y0 = 0.f;

    for (int t0 = 0; t0 < T; t0 += 4) {
        const int cb = t0 >> 2;
        float4 rb[9], vb[6], ub[6];
#pragma unroll
        for (int q = 0; q < 9; ++q) rb[q] = r4[cb * 9 + q];
#pragma unroll
        for (int q = 0; q < 6; ++q) vb[q] = v4[cb * 6 + q];
#pragma unroll
        for (int q = 0; q < 6; ++q) ub[q] = u4[cb * 6 + q];
        float rf[36], vf[24], uf[24];
#pragma unroll
        for (int q = 0; q < 9; ++q) {
            rf[4 * q] = rb[q].x; rf[4 * q + 1] = rb[q].y;
            rf[4 * q + 2] = rb[q].z; rf[4 * q + 3] = rb[q].w;
        }
#pragma unroll
        for (int q = 0; q < 6; ++q) {
            vf[4 * q] = vb[q].x; vf[4 * q + 1] = vb[q].y;
            vf[4 * q + 2] = vb[q].z; vf[4 * q + 3] = vb[q].w;
            uf[4 * q] = ub[q].x; uf[4 * q + 1] = ub[q].y;
            uf[4 * q + 2] = ub[q].z; uf[4 * q + 3] = ub[q].w;
        }
#pragma unroll
        for (int dt = 0; dt < 4; ++dt) {
            float x[21];
#pragma unroll
            for (int j = 0; j < 9; ++j) x[j] = rf[dt * 9 + j];
#pragma unroll
            for (int j = 0; j < 6; ++j) x[9 + j] = vf[dt * 6 + j];
#pragma unroll
            for (int j = 0; j < 6; ++j) x[15 + j] = uf[dt * 6 + j];
            float gt[4];
#pragma unroll
            for (int g = 0; g < 4; ++g) {
                float a = whh[0][g] * h[0];
#pragma unroll
                for (int j = 0; j < 21; ++j) a = fmaf(wi0[g][j], x[j], a);
                gt[g] = a;
            }
            {
                float ii = sigm(gt[0]), ff = sigm(gt[1]);
                float gg = tanh_fast(gt[2]), oo = sigm(gt[3]);
                c[0] = ff * c[0] + ii * gg;
                h[0] = oo * tanh_fast(c[0]);
            }
            float xin = h[0];
#pragma unroll
            for (int l = 1; l < 5; ++l) {
                float b0 = fmaf(wir[l - 1][0], xin, whh[l][0] * h[l]);
                float b1 = fmaf(wir[l - 1][1], xin, whh[l][1] * h[l]);
                float b2 = fmaf(wir[l - 1][2], xin, whh[l][2] * h[l]);
                float b3 = fmaf(wir[l - 1][3], xin, whh[l][3] * h[l]);
                float ii = sigm(b0), ff = sigm(b1);
                float gg = tanh_fast(b2), oo = sigm(b3);
                c[l] = ff * c[l] + ii * gg;
                h[l] = oo * tanh_fast(c[l]);
                xin = h[l];
            }
            if (t0 + dt == 0) y0 = h[4];
        }
    }
#pragma unroll
    for (int l = 0; l < 5; ++l) {
        out[(size_t)6 * k + (size_t)l * k + s] = h[l];
        out[(size_t)11 * k + (size_t)l * k + s] = c[l];
    }
    wsy[s] = y0;
    float ys = y0, yq = y0 * y0;
#pragma unroll
    for (int off = 32; off; off >>= 1) {
        ys += __shfl_down(ys, off);
        yq += __shfl_down(yq, off);
    }
    __shared__ float pS[4], pQ[4];
    const int wid = threadIdx.x >> 6, lane = threadIdx.x & 63;
    if (lane == 0) { pS[wid] = ys; pQ[wid] = yq; }
    __syncthreads();
    if (threadIdx.x == 0) {
        atomicAdd(&wsd[0], (double)(pS[0] + pS[1] + pS[2] + pS[3]));
        atomicAdd(&wsd[1], (double)(pQ[0] + pQ[1] + pQ[2] + pQ[3]));
    }
}

// ---------------- FC chain ---------------------------------------------------
__global__ __launch_bounds__(256)
void hist_kernel(const float* __restrict__ W1, const float* __restrict__ g1,
                 const float* __restrict__ b1, double* __restrict__ wsd,
                 const float* __restrict__ wsy, int k)
{
    __shared__ float sTau[32];
    __shared__ float sH[3 * NREG];
    __shared__ float sMy;
    const int tid = threadIdx.x;
    if (tid < 3 * NREG) sH[tid] = 0.f;
    if (tid < 32) {
        float my, vy, a, b, tau; int flip;
        bn1_params(W1, g1, b1, wsd, k, tid, my, vy, a, b, tau, flip);
        sTau[tid] = tau;
        if (tid == 0) sMy = my;
    }
    __syncthreads();
    const int stride = gridDim.x * 256;
    for (int s = blockIdx.x * 256 + tid; s < k; s += stride) {
        const float y = wsy[s];
        const float yc = y - sMy;
        int rgn = 0;
#pragma unroll
        for (int j = 0; j < 32; ++j) rgn += (y > sTau[j]) ? 1 : 0;
        atomicAdd(&sH[rgn], 1.0f);
        atomicAdd(&sH[NREG + rgn], yc);
        atomicAdd(&sH[2 * NREG + rgn], yc * yc);
    }
    __syncthreads();
    if (tid < 3 * NREG) atomicAdd(&wsd[2 + tid], (double)sH[tid]);
}

__global__ __launch_bounds__(256)
void tables_kernel(const float* __restrict__ W1, const float* __restrict__ g1,
                   const float* __restrict__ b1, const float* __restrict__ W2,
                   const float* __restrict__ g2, const float* __restrict__ b2,
                   const double* __restrict__ wsd, float* __restrict__ gPQ, int k)
{
    __shared__ float sA[32], sB[32], sTau[32];
    __shared__ int sRank[32], sFlip[32];
    __shared__ float sS0[NREG], sS1[NREG], sS2[NREG];
    __shared__ float sW2[1024];
    __shared__ float sSumY1[32];
    __shared__ float sM[1024];
    __shared__ float sI2[32], sM2v[32], sB2[32];
    const int tid = threadIdx.x;

    for (int i = tid; i < 1024; i += 256) sW2[i] = W2[i];
    if (tid < NREG) {
        sS0[tid] = (float)wsd[2 + tid];
        sS1[tid] = (float)wsd[2 + NREG + tid];
        sS2[tid] = (float)wsd[2 + 2 * NREG + tid];
    }
    if (tid < 32) {
        float my, vy, a, b, tau; int flip;
        bn1_params(W1, g1, b1, wsd, k, tid, my, vy, a, b, tau, flip);
        sA[tid] = a; sB[tid] = b; sTau[tid] = tau; sFlip[tid] = flip;
        sB2[tid] = b2[tid];
    }
    __syncthreads();
    if (tid < 32) {
        int rk = 0;
        float tj = sTau[tid];
#pragma unroll
        for (int l = 0; l < 32; ++l)
            rk += (sTau[l] < tj || (sTau[l] == tj && l < tid)) ? 1 : 0;
        sRank[tid] = rk;
    }
    __syncthreads();
    if (tid < 32) {
        const int rk = sRank[tid], fl = sFlip[tid];
        const float a = sA[tid], b = sB[tid];
        float acc = 0.f;
        for (int rg = 0; rg < NREG; ++rg) {
            float m = (((rk < rg) ? 1 : 0) != fl) ? 1.0f : NEGS;
            acc += m * (a * sS1[rg] + b * sS0[rg]);
        }
        sSumY1[tid] = acc;
    }
    for (int p = tid; p < 1024; p += 256) {
        const int j = p >> 5, l = p & 31;
        const int rj = sRank[j], fj = sFlip[j];
        const int rl = sRank[l], flp = sFlip[l];
        const float aj = sA[j], bj = sB[j], al = sA[l], bl = sB[l];
        const float caa = aj * al, cab = aj * bl + al * bj, cbb = bj * bl;
        float acc = 0.f;
        for (int rg = 0; rg < NREG; ++rg) {
            float mj = (((rj < rg) ? 1 : 0) != fj) ? 1.0f : NEGS;
            float ml = (((rl < rg) ? 1 : 0) != flp) ? 1.0f : NEGS;
            acc += mj * ml * (caa * sS2[rg] + cab * sS1[rg] + cbb * sS0[rg]);
        }
        sM[p] = acc;
    }
    __syncthreads();
    if (tid < 32) {
        const int i = tid;
        float s2 = 0.f, ss2 = 0.f;
#pragma unroll
        for (int j = 0; j < 32; ++j) {
            float wij = sW2[i * 32 + j];
            s2 = fmaf(wij, sSumY1[j], s2);
            float tj = 0.f;
#pragma unroll
            for (int l = 0; l < 32; ++l) tj = fmaf(sW2[i * 32 + l], sM[j * 32 + l], tj);
            ss2 = fmaf(wij, tj, ss2);
        }
        float m2 = s2 / k;
        float v2 = ss2 / k - m2 * m2;
        sM2v[i] = m2;
        sI2[i] = g2[i] * rsqrtf(v2 + EPS);
    }
    __syncthreads();
    for (int idx = tid; idx < NREG * 32; idx += 256) {
        const int rg = idx >> 5, i = idx & 31;
        float Ai = 0.f, Bi = 0.f;
#pragma unroll
        for (int j = 0; j < 32; ++j) {
            float m = (((sRank[j] < rg) ? 1 : 0) != sFlip[j]) ? 1.0f : NEGS;
            float w = sW2[i * 32 + j] * m;
            Ai = fmaf(w, sA[j], Ai);
            Bi = fmaf(w, sB[j], Bi);
        }
        gPQ[idx] = sI2[i] * Ai;
        gPQ[NREG * 32 + idx] = sI2[i] * (Bi - sM2v[i]) + sB2[i];
    }
}

__global__ __launch_bounds__(256)
void final_kernel(const float* __restrict__ W1, const float* __restrict__ g1,
                  const float* __restrict__ b1, const float* __restrict__ W3,
                  const double* __restrict__ wsd, const float* __restrict__ wsy,
                  const float* __restrict__ gPQ, float* __restrict__ out, int k)
{
    __shared__ float sTau[32], sW3[192], sMy;
    __shared__ float sP[NREG][33], sQ[NREG][33];
    const int tid = threadIdx.x;
    for (int idx = tid; idx < NREG * 32; idx += 256) {
        const int rg = idx >> 5, i = idx & 31;
        sP[rg][i] = gPQ[idx];
        sQ[rg][i] = gPQ[NREG * 32 + idx];
    }
    if (tid < 192) sW3[tid] = W3[tid];
    if (tid < 32) {
        float my, vy, a, b, tau; int flip;
        bn1_params(W1, g1, b1, wsd, k, tid, my, vy, a, b, tau, flip);
        sTau[tid] = tau;
        if (tid == 0) sMy = my;
    }
    __syncthreads();
    const int s = blockIdx.x * 256 + tid;
    const float y = wsy[s];
    const float yc = y - sMy;
    int rgn = 0;
#pragma unroll
    for (int j = 0; j < 32; ++j) rgn += (y > sTau[j]) ? 1 : 0;
    float dv[6] = {0.f, 0.f, 0.f, 0.f, 0.f, 0.f};
#pragma unroll
    for (int i = 0; i < 32; ++i) {
        float y2 = lrelu(fmaf(sP[rgn][i], yc, sQ[rgn][i]));
#pragma unroll
        for (int m = 0; m < 6; ++m) dv[m] = fmaf(sW3[m * 32 + i], y2, dv[m]);
    }
#pragma unroll
    for (int m = 0; m < 6; ++m) out[(size_t)s * 6 + m] = dv[m];
}

extern "C" void kernel_launch(void* const* d_in, const int* in_sizes, int n_in,
                              void* d_out, int out_size, void* d_ws, size_t ws_size,
                              hipStream_t stream)
{
    const float* r    = (const float*)d_in[0];
    const float* v    = (const float*)d_in[1];
    const float* u    = (const float*)d_in[2];
    const float* wih0 = (const float*)d_in[3];
    const float* wihr = (const float*)d_in[4];
    const float* whhp = (const float*)d_in[5];
    const float* W1   = (const float*)d_in[6];
    const float* g1v  = (const float*)d_in[7];
    const float* b1v  = (const float*)d_in[8];
    const float* W2   = (const float*)d_in[9];
    const float* g2v  = (const float*)d_in[10];
    const float* b2v  = (const float*)d_in[11];
    const float* W3   = (const float*)d_in[12];

    const int k = in_sizes[0] / (T * 9);   // 65536
    float* out = (float*)d_out;
    double* wsd = (double*)d_ws;
    float* wsy = (float*)((char*)d_ws + 1024);

    const size_t xg_off = 1024 + (size_t)k * 4;
    const size_t need = xg_off + (size_t)k * T * 16 + (size_t)NREG * 32 * 2 * 4;

    hipMemsetAsync(d_ws, 0, 1024, stream);

    const int blocks = k / 256;
    float* gPQ;
    if (ws_size >= need) {
        float4* xg = (float4*)((char*)d_ws + xg_off);
        gPQ = (float*)((char*)d_ws + xg_off + (size_t)k * T * 16);
        const int ngroups = k / 8;
        int pblocks = 1536;                 // 6 blocks/CU (LDS-limited)
        if (pblocks > ngroups) pblocks = ngroups;
        gates_kernel<<<pblocks, 256, 0, stream>>>(r, v, u, wih0, xg, k, ngroups);
        recur_kernel<<<blocks, 256, 0, stream>>>(xg, wihr, whhp, out, wsd, wsy, k);
    } else {
        gPQ = (float*)((char*)d_ws + xg_off);
        lstm_fused<<<blocks, 256, 0, stream>>>(r, v, u, wih0, wihr, whhp, out, wsd, wsy, k);
    }
    hist_kernel<<<64, 256, 0, stream>>>(W1, g1v, b1v, wsd, wsy, k);
    tables_kernel<<<1, 256, 0, stream>>>(W1, g1v, b1v, W2, g2v, b2v, wsd, gPQ, k);
    final_kernel<<<blocks, 256, 0, stream>>>(W1, g1v, b1v, W3, wsd, wsy, gPQ, out, k);
}

// Round 5
// 262.725 us; speedup vs baseline: 1.0149x; 1.0149x over previous
//
#include <hip/hip_runtime.h>
#include <math.h>

#define T 32
#define NEGS 0.1f
#define EPS 1e-5f
#define NREG 33

// ws layout:
//   [0,1024): double accum[101]: [0]=sum_y [1]=sum_y2 [2..100]=hist S0/S1/S2
//   [1024, 1024+4k): float y[k]
//   [1024+4k, ...): float gPQ[2*NREG*32]

__device__ __forceinline__ float rcp_fast(float x) { return __builtin_amdgcn_rcpf(x); }
__device__ __forceinline__ float sigm(float x) { return rcp_fast(1.0f + __expf(-x)); }
__device__ __forceinline__ float tanh_fast(float x) {
    float t = __expf(2.0f * fabsf(x));
    float r = 1.0f - 2.0f * rcp_fast(t + 1.0f);
    return copysignf(r, x);
}
__device__ __forceinline__ float lrelu(float x) { return x > 0.0f ? x : NEGS * x; }

__device__ __forceinline__ void bn1_params(const float* __restrict__ W1,
                                           const float* __restrict__ g1,
                                           const float* __restrict__ b1,
                                           const double* __restrict__ wsd, int k, int j,
                                           float& my, float& vy, float& a, float& b,
                                           float& tau, int& flip)
{
    my = (float)(wsd[0] / k);
    vy = (float)(wsd[1] / k) - my * my;
    float wj = W1[j];
    a = g1[j] * wj * rsqrtf(fmaf(wj * wj, vy, EPS));
    b = b1[j];
    if (a > 0.0f)      { tau = my - b / a; flip = 0; }
    else if (a < 0.0f) { tau = my - b / a; flip = 1; }
    else               { tau = (b > 0.0f ? -__builtin_inff() : __builtin_inff()); flip = 0; }
}

// ---------------- Fused gates + recurrence -----------------------------------
// Three different gates_kernel structures all hit ~70 us at ~2.9 TB/s
// delivered; the two-kernel split also round-trips 67 MB of xg. Fuse:
// block = 256 threads = 256 samples. For each group of 8 samples: stage
// the group's 25.6 KB input into LDS with coalesced float4 loads (next
// group's loads prefetched into registers before the barrier), compute
// all 8x32 gate vectors (1 thread <-> 1 (sample,t)), transpose through
// padded LDS pbuf so the 8 owner threads collect their 32 gate-float4s
// into registers. Then run the recurrence entirely from registers.
// Eliminates xg (33.5 MB write + 33.5 MB read) and one dispatch.
__global__ __launch_bounds__(256, 1)
void fused_kernel(const float* __restrict__ r, const float* __restrict__ v,
                  const float* __restrict__ u, const float* __restrict__ wih0,
                  const float* __restrict__ wihr, const float* __restrict__ whhp,
                  float* __restrict__ out, double* __restrict__ wsd,
                  float* __restrict__ wsy, int k)
{
    __shared__ float rbuf[8 * 32 * 9];     // 9216 B
    __shared__ float vbuf[8 * 32 * 6];     // 6144 B
    __shared__ float ubuf[8 * 32 * 6];     // 6144 B
    __shared__ float4 pbuf[32][9];         // 4608 B  (pad 8->9: conflict-free)
    const int tid = threadIdx.x;
    const int sBase = blockIdx.x * 256;

    float4* rb4 = reinterpret_cast<float4*>(rbuf);
    float4* vb4 = reinterpret_cast<float4*>(vbuf);
    float4* ub4 = reinterpret_cast<float4*>(ubuf);

    // uniform weights -> scalar registers
    float wi0[4][21];
#pragma unroll
    for (int g = 0; g < 4; ++g)
#pragma unroll
        for (int j = 0; j < 21; ++j) wi0[g][j] = wih0[g * 21 + j];
    float wir[4][4];
#pragma unroll
    for (int l = 0; l < 4; ++l)
#pragma unroll
        for (int g = 0; g < 4; ++g) wir[l][g] = wihr[l * 4 + g];
    float whh[5][4];
#pragma unroll
    for (int l = 0; l < 5; ++l)
#pragma unroll
        for (int g = 0; g < 4; ++g) whh[l][g] = whhp[l * 4 + g];

    // per-thread gate storage: this thread's sample, all 32 timesteps
    float4 gbuf[T];

    // prefetch registers for one 8-sample group (28 VGPRs)
    float4 Ra0, Ra1, Ra2, Rv0, Rv1, Ru0, Ru1;

#define ISSUE_GROUP(gg)                                                         \
    do {                                                                        \
        const int s0_ = sBase + (gg) * 8;                                       \
        const float4* r4_ = reinterpret_cast<const float4*>(r + (size_t)s0_ * (T * 9)); \
        const float4* v4_ = reinterpret_cast<const float4*>(v + (size_t)s0_ * (T * 6)); \
        const float4* u4_ = reinterpret_cast<const float4*>(u + (size_t)s0_ * (T * 6)); \
        Ra0 = r4_[tid];                                                         \
        Ra1 = r4_[256 + tid];                                                   \
        if (tid < 64) Ra2 = r4_[512 + tid];                                     \
        Rv0 = v4_[tid];                                                         \
        if (tid < 128) Rv1 = v4_[256 + tid];                                    \
        Ru0 = u4_[tid];                                                         \
        if (tid < 128) Ru1 = u4_[256 + tid];                                    \
    } while (0)

    ISSUE_GROUP(0);

    for (int sg = 0; sg < 32; ++sg) {
        // commit prefetched regs to LDS (hw waits vmcnt for these regs)
        rb4[tid] = Ra0;
        rb4[256 + tid] = Ra1;
        if (tid < 64) rb4[512 + tid] = Ra2;
        vb4[tid] = Rv0;
        if (tid < 128) vb4[256 + tid] = Rv1;
        ub4[tid] = Ru0;
        if (tid < 128) ub4[256 + tid] = Ru1;

        // issue NEXT group's loads; they fly under the compute below
        if (sg < 31) ISSUE_GROUP(sg + 1);

        __syncthreads();   // staging visible (also orders pbuf readout < pbuf write)

        // thread <-> (sample-in-group sl, timestep t)
        const int sl = tid >> 5, t = tid & 31;
        float x[21];
#pragma unroll
        for (int j = 0; j < 9; ++j) x[j] = rbuf[sl * (32 * 9) + t * 9 + j];
#pragma unroll
        for (int j = 0; j < 6; ++j) x[9 + j] = vbuf[sl * (32 * 6) + t * 6 + j];
#pragma unroll
        for (int j = 0; j < 6; ++j) x[15 + j] = ubuf[sl * (32 * 6) + t * 6 + j];

        float4 g4;
        float* gp = (float*)&g4;
#pragma unroll
        for (int gi = 0; gi < 4; ++gi) {
            float acc = 0.f;
#pragma unroll
            for (int j = 0; j < 21; ++j) acc = fmaf(wi0[gi][j], x[j], acc);
            gp[gi] = acc;
        }
        pbuf[t][sl] = g4;
        __syncthreads();   // pbuf ready; also orders rbuf reads < next commit

        // the 8 owner threads of this group collect their gates
        if ((tid >> 3) == sg) {
            const int l = tid & 7;
#pragma unroll
            for (int tt = 0; tt < T; ++tt) gbuf[tt] = pbuf[tt][l];
        }
    }
#undef ISSUE_GROUP

    // ---------------- recurrence (all gates in registers) ----------------
    const int s = sBase + tid;
    float h[5] = {0.f, 0.f, 0.f, 0.f, 0.f};
    float c[5] = {0.f, 0.f, 0.f, 0.f, 0.f};
    float y0 = 0.f;

#pragma unroll
    for (int t = 0; t < T; ++t) {
        const float4 G = gbuf[t];
        float a0 = fmaf(whh[0][0], h[0], G.x);
        float a1 = fmaf(whh[0][1], h[0], G.y);
        float a2 = fmaf(whh[0][2], h[0], G.z);
        float a3 = fmaf(whh[0][3], h[0], G.w);
        {
            float ii = sigm(a0), ff = sigm(a1);
            float gg = tanh_fast(a2), oo = sigm(a3);
            c[0] = ff * c[0] + ii * gg;
            h[0] = oo * tanh_fast(c[0]);
        }
        float xin = h[0];
#pragma unroll
        for (int l = 1; l < 5; ++l) {
            float b0 = fmaf(wir[l - 1][0], xin, whh[l][0] * h[l]);
            float b1 = fmaf(wir[l - 1][1], xin, whh[l][1] * h[l]);
            float b2 = fmaf(wir[l - 1][2], xin, whh[l][2] * h[l]);
            float b3 = fmaf(wir[l - 1][3], xin, whh[l][3] * h[l]);
            float ii = sigm(b0), ff = sigm(b1);
            float gg = tanh_fast(b2), oo = sigm(b3);
            c[l] = ff * c[l] + ii * gg;
            h[l] = oo * tanh_fast(c[l]);
            xin = h[l];
        }
        if (t == 0) y0 = h[4];
    }

#pragma unroll
    for (int l = 0; l < 5; ++l) {
        out[(size_t)6 * k + (size_t)l * k + s] = h[l];
        out[(size_t)11 * k + (size_t)l * k + s] = c[l];
    }
    wsy[s] = y0;

    float ys = y0, yq = y0 * y0;
#pragma unroll
    for (int off = 32; off; off >>= 1) {
        ys += __shfl_down(ys, off);
        yq += __shfl_down(yq, off);
    }
    __shared__ float pS[4], pQ[4];
    const int wid = threadIdx.x >> 6, lane = threadIdx.x & 63;
    if (lane == 0) { pS[wid] = ys; pQ[wid] = yq; }
    __syncthreads();
    if (threadIdx.x == 0) {
        atomicAdd(&wsd[0], (double)(pS[0] + pS[1] + pS[2] + pS[3]));
        atomicAdd(&wsd[1], (double)(pQ[0] + pQ[1] + pQ[2] + pQ[3]));
    }
}

// ---------------- FC chain ---------------------------------------------------
__global__ __launch_bounds__(256)
void hist_kernel(const float* __restrict__ W1, const float* __restrict__ g1,
                 const float* __restrict__ b1, double* __restrict__ wsd,
                 const float* __restrict__ wsy, int k)
{
    __shared__ float sTau[32];
    __shared__ float sH[3 * NREG];
    __shared__ float sMy;
    const int tid = threadIdx.x;
    if (tid < 3 * NREG) sH[tid] = 0.f;
    if (tid < 32) {
        float my, vy, a, b, tau; int flip;
        bn1_params(W1, g1, b1, wsd, k, tid, my, vy, a, b, tau, flip);
        sTau[tid] = tau;
        if (tid == 0) sMy = my;
    }
    __syncthreads();
    const int stride = gridDim.x * 256;
    for (int s = blockIdx.x * 256 + tid; s < k; s += stride) {
        const float y = wsy[s];
        const float yc = y - sMy;
        int rgn = 0;
#pragma unroll
        for (int j = 0; j < 32; ++j) rgn += (y > sTau[j]) ? 1 : 0;
        atomicAdd(&sH[rgn], 1.0f);
        atomicAdd(&sH[NREG + rgn], yc);
        atomicAdd(&sH[2 * NREG + rgn], yc * yc);
    }
    __syncthreads();
    if (tid < 3 * NREG) atomicAdd(&wsd[2 + tid], (double)sH[tid]);
}

__global__ __launch_bounds__(256)
void tables_kernel(const float* __restrict__ W1, const float* __restrict__ g1,
                   const float* __restrict__ b1, const float* __restrict__ W2,
                   const float* __restrict__ g2, const float* __restrict__ b2,
                   const double* __restrict__ wsd, float* __restrict__ gPQ, int k)
{
    __shared__ float sA[32], sB[32], sTau[32];
    __shared__ int sRank[32], sFlip[32];
    __shared__ float sS0[NREG], sS1[NREG], sS2[NREG];
    __shared__ float sW2[1024];
    __shared__ float sSumY1[32];
    __shared__ float sM[1024];
    __shared__ float sI2[32], sM2v[32], sB2[32];
    const int tid = threadIdx.x;

    for (int i = tid; i < 1024; i += 256) sW2[i] = W2[i];
    if (tid < NREG) {
        sS0[tid] = (float)wsd[2 + tid];
        sS1[tid] = (float)wsd[2 + NREG + tid];
        sS2[tid] = (float)wsd[2 + 2 * NREG + tid];
    }
    if (tid < 32) {
        float my, vy, a, b, tau; int flip;
        bn1_params(W1, g1, b1, wsd, k, tid, my, vy, a, b, tau, flip);
        sA[tid] = a; sB[tid] = b; sTau[tid] = tau; sFlip[tid] = flip;
        sB2[tid] = b2[tid];
    }
    __syncthreads();
    if (tid < 32) {
        int rk = 0;
        float tj = sTau[tid];
#pragma unroll
        for (int l = 0; l < 32; ++l)
            rk += (sTau[l] < tj || (sTau[l] == tj && l < tid)) ? 1 : 0;
        sRank[tid] = rk;
    }
    __syncthreads();
    if (tid < 32) {
        const int rk = sRank[tid], fl = sFlip[tid];
        const float a = sA[tid], b = sB[tid];
        float acc = 0.f;
        for (int rg = 0; rg < NREG; ++rg) {
            float m = (((rk < rg) ? 1 : 0) != fl) ? 1.0f : NEGS;
            acc += m * (a * sS1[rg] + b * sS0[rg]);
        }
        sSumY1[tid] = acc;
    }
    for (int p = tid; p < 1024; p += 256) {
        const int j = p >> 5, l = p & 31;
        const int rj = sRank[j], fj = sFlip[j];
        const int rl = sRank[l], flp = sFlip[l];
        const float aj = sA[j], bj = sB[j], al = sA[l], bl = sB[l];
        const float caa = aj * al, cab = aj * bl + al * bj, cbb = bj * bl;
        float acc = 0.f;
        for (int rg = 0; rg < NREG; ++rg) {
            float mj = (((rj < rg) ? 1 : 0) != fj) ? 1.0f : NEGS;
            float ml = (((rl < rg) ? 1 : 0) != flp) ? 1.0f : NEGS;
            acc += mj * ml * (caa * sS2[rg] + cab * sS1[rg] + cbb * sS0[rg]);
        }
        sM[p] = acc;
    }
    __syncthreads();
    if (tid < 32) {
        const int i = tid;
        float s2 = 0.f, ss2 = 0.f;
#pragma unroll
        for (int j = 0; j < 32; ++j) {
            float wij = sW2[i * 32 + j];
            s2 = fmaf(wij, sSumY1[j], s2);
            float tj = 0.f;
#pragma unroll
            for (int l = 0; l < 32; ++l) tj = fmaf(sW2[i * 32 + l], sM[j * 32 + l], tj);
            ss2 = fmaf(wij, tj, ss2);
        }
        float m2 = s2 / k;
        float v2 = ss2 / k - m2 * m2;
        sM2v[i] = m2;
        sI2[i] = g2[i] * rsqrtf(v2 + EPS);
    }
    __syncthreads();
    for (int idx = tid; idx < NREG * 32; idx += 256) {
        const int rg = idx >> 5, i = idx & 31;
        float Ai = 0.f, Bi = 0.f;
#pragma unroll
        for (int j = 0; j < 32; ++j) {
            float m = (((sRank[j] < rg) ? 1 : 0) != sFlip[j]) ? 1.0f : NEGS;
            float w = sW2[i * 32 + j] * m;
            Ai = fmaf(w, sA[j], Ai);
            Bi = fmaf(w, sB[j], Bi);
        }
        gPQ[idx] = sI2[i] * Ai;
        gPQ[NREG * 32 + idx] = sI2[i] * (Bi - sM2v[i]) + sB2[i];
    }
}

__global__ __launch_bounds__(256)
void final_kernel(const float* __restrict__ W1, const float* __restrict__ g1,
                  const float* __restrict__ b1, const float* __restrict__ W3,
                  const double* __restrict__ wsd, const float* __restrict__ wsy,
                  const float* __restrict__ gPQ, float* __restrict__ out, int k)
{
    __shared__ float sTau[32], sW3[192], sMy;
    __shared__ float sP[NREG][33], sQ[NREG][33];
    const int tid = threadIdx.x;
    for (int idx = tid; idx < NREG * 32; idx += 256) {
        const int rg = idx >> 5, i = idx & 31;
        sP[rg][i] = gPQ[idx];
        sQ[rg][i] = gPQ[NREG * 32 + idx];
    }
    if (tid < 192) sW3[tid] = W3[tid];
    if (tid < 32) {
        float my, vy, a, b, tau; int flip;
        bn1_params(W1, g1, b1, wsd, k, tid, my, vy, a, b, tau, flip);
        sTau[tid] = tau;
        if (tid == 0) sMy = my;
    }
    __syncthreads();
    const int s = blockIdx.x * 256 + tid;
    const float y = wsy[s];
    const float yc = y - sMy;
    int rgn = 0;
#pragma unroll
    for (int j = 0; j < 32; ++j) rgn += (y > sTau[j]) ? 1 : 0;
    float dv[6] = {0.f, 0.f, 0.f, 0.f, 0.f, 0.f};
#pragma unroll
    for (int i = 0; i < 32; ++i) {
        float y2 = lrelu(fmaf(sP[rgn][i], yc, sQ[rgn][i]));
#pragma unroll
        for (int m = 0; m < 6; ++m) dv[m] = fmaf(sW3[m * 32 + i], y2, dv[m]);
    }
#pragma unroll
    for (int m = 0; m < 6; ++m) out[(size_t)s * 6 + m] = dv[m];
}

extern "C" void kernel_launch(void* const* d_in, const int* in_sizes, int n_in,
                              void* d_out, int out_size, void* d_ws, size_t ws_size,
                              hipStream_t stream)
{
    const float* r    = (const float*)d_in[0];
    const float* v    = (const float*)d_in[1];
    const float* u    = (const float*)d_in[2];
    const float* wih0 = (const float*)d_in[3];
    const float* wihr = (const float*)d_in[4];
    const float* whhp = (const float*)d_in[5];
    const float* W1   = (const float*)d_in[6];
    const float* g1v  = (const float*)d_in[7];
    const float* b1v  = (const float*)d_in[8];
    const float* W2   = (const float*)d_in[9];
    const float* g2v  = (const float*)d_in[10];
    const float* b2v  = (const float*)d_in[11];
    const float* W3   = (const float*)d_in[12];

    const int k = in_sizes[0] / (T * 9);   // 65536
    float* out = (float*)d_out;
    double* wsd = (double*)d_ws;
    float* wsy = (float*)((char*)d_ws + 1024);
    float* gPQ = (float*)((char*)d_ws + 1024 + (size_t)k * 4);

    hipMemsetAsync(d_ws, 0, 1024, stream);

    const int blocks = k / 256;
    fused_kernel<<<blocks, 256, 0, stream>>>(r, v, u, wih0, wihr, whhp,
                                             out, wsd, wsy, k);
    hist_kernel<<<64, 256, 0, stream>>>(W1, g1v, b1v, wsd, wsy, k);
    tables_kernel<<<1, 256, 0, stream>>>(W1, g1v, b1v, W2, g2v, b2v, wsd, gPQ, k);
    final_kernel<<<blocks, 256, 0, stream>>>(W1, g1v, b1v, W3, wsd, wsy, gPQ, out, k);
}

// Round 6
// 256.699 us; speedup vs baseline: 1.0387x; 1.0235x over previous
//
#include <hip/hip_runtime.h>
#include <math.h>

#define T 32
#define NEGS 0.1f
#define EPS 1e-5f
#define NREG 33

// ws layout:
//   [0,1024): double accum[101]: [0]=sum_y [1]=sum_y2 [2..100]=hist S0/S1/S2
//   [1024, 1024+4k): float y[k]
//   [1024+4k, ...): float gPQ[2*NREG*32]

__device__ __forceinline__ float rcp_fast(float x) { return __builtin_amdgcn_rcpf(x); }
__device__ __forceinline__ float sigm(float x) { return rcp_fast(1.0f + __expf(-x)); }
__device__ __forceinline__ float tanh_fast(float x) {
    float t = __expf(2.0f * fabsf(x));
    float r = 1.0f - 2.0f * rcp_fast(t + 1.0f);
    return copysignf(r, x);
}
__device__ __forceinline__ float lrelu(float x) { return x > 0.0f ? x : NEGS * x; }

__device__ __forceinline__ void bn1_params(const float* __restrict__ W1,
                                           const float* __restrict__ g1,
                                           const float* __restrict__ b1,
                                           const double* __restrict__ wsd, int k, int j,
                                           float& my, float& vy, float& a, float& b,
                                           float& tau, int& flip)
{
    my = (float)(wsd[0] / k);
    vy = (float)(wsd[1] / k) - my * my;
    float wj = W1[j];
    a = g1[j] * wj * rsqrtf(fmaf(wj * wj, vy, EPS));
    b = b1[j];
    if (a > 0.0f)      { tau = my - b / a; flip = 0; }
    else if (a < 0.0f) { tau = my - b / a; flip = 1; }
    else               { tau = (b > 0.0f ? -__builtin_inff() : __builtin_inff()); flip = 0; }
}

// ---------------- Fused gates + recurrence -----------------------------------
// Double-buffered LDS staging (one barrier per group instead of two) +
// depth-2 register prefetch. Per group sg (parity p = sg&1, reg set A/B):
//   1. commit reg set -> buf[p]   (its loads were issued 2 groups ago)
//   2. reissue that reg set for group sg+2
//   3. __syncthreads()            (the ONLY barrier per group)
//   4. owners of group sg-1 collect gates from pbuf[1-p]
//   5. compute gates from buf[p], write pbuf[p]
// Hazards: buf[p] commit->read same iter (barrier 3); buf[p] read(iter sg)
// vs commit(iter sg+2) separated by barriers sg+1,sg+2; pbuf[p] write(sg)
// vs read(sg+1) by barrier sg+1; pbuf read(sg+1) vs write(sg+2) by barrier
// sg+2. All ordered. Steady-state in-flight: 2x7x16Bx64 = 14 KB/wave.
__global__ __launch_bounds__(256, 1)
void fused_kernel(const float* __restrict__ r, const float* __restrict__ v,
                  const float* __restrict__ u, const float* __restrict__ wih0,
                  const float* __restrict__ wihr, const float* __restrict__ whhp,
                  float* __restrict__ out, double* __restrict__ wsd,
                  float* __restrict__ wsy, int k)
{
    __shared__ float rbuf[2][8 * 32 * 9];   // 18432 B
    __shared__ float vbuf[2][8 * 32 * 6];   // 12288 B
    __shared__ float ubuf[2][8 * 32 * 6];   // 12288 B
    __shared__ float4 pbuf[2][32][9];       //  9216 B (pad 8->9: conflict-free)
    const int tid = threadIdx.x;
    const int sBase = blockIdx.x * 256;

    // uniform weights -> scalar registers
    float wi0[4][21];
#pragma unroll
    for (int g = 0; g < 4; ++g)
#pragma unroll
        for (int j = 0; j < 21; ++j) wi0[g][j] = wih0[g * 21 + j];
    float wir[4][4];
#pragma unroll
    for (int l = 0; l < 4; ++l)
#pragma unroll
        for (int g = 0; g < 4; ++g) wir[l][g] = wihr[l * 4 + g];
    float whh[5][4];
#pragma unroll
    for (int l = 0; l < 5; ++l)
#pragma unroll
        for (int g = 0; g < 4; ++g) whh[l][g] = whhp[l * 4 + g];

    // per-thread gate storage: this thread's sample, all 32 timesteps
    float4 gbuf[T];

    // two prefetch register sets (7 float4 each)
    float4 Aa0, Aa1, Aa2, Av0, Av1, Au0, Au1;
    float4 Ba0, Ba1, Ba2, Bv0, Bv1, Bu0, Bu1;

#define ISSUE(gg, R0, R1, R2, V0, V1, U0, U1)                                   \
    do {                                                                        \
        const int s0_ = sBase + (gg) * 8;                                       \
        const float4* r4_ = reinterpret_cast<const float4*>(r + (size_t)s0_ * (T * 9)); \
        const float4* v4_ = reinterpret_cast<const float4*>(v + (size_t)s0_ * (T * 6)); \
        const float4* u4_ = reinterpret_cast<const float4*>(u + (size_t)s0_ * (T * 6)); \
        R0 = r4_[tid];                                                          \
        R1 = r4_[256 + tid];                                                    \
        if (tid < 64) R2 = r4_[512 + tid];                                      \
        V0 = v4_[tid];                                                          \
        if (tid < 128) V1 = v4_[256 + tid];                                     \
        U0 = u4_[tid];                                                          \
        if (tid < 128) U1 = u4_[256 + tid];                                     \
    } while (0)

#define BODY(sg, p, R0, R1, R2, V0, V1, U0, U1)                                 \
    do {                                                                        \
        float4* rb4_ = reinterpret_cast<float4*>(rbuf[p]);                      \
        float4* vb4_ = reinterpret_cast<float4*>(vbuf[p]);                      \
        float4* ub4_ = reinterpret_cast<float4*>(ubuf[p]);                      \
        rb4_[tid] = R0;                                                         \
        rb4_[256 + tid] = R1;                                                   \
        if (tid < 64) rb4_[512 + tid] = R2;                                     \
        vb4_[tid] = V0;                                                         \
        if (tid < 128) vb4_[256 + tid] = V1;                                    \
        ub4_[tid] = U0;                                                         \
        if (tid < 128) ub4_[256 + tid] = U1;                                    \
        if ((sg) + 2 < 32) ISSUE((sg) + 2, R0, R1, R2, V0, V1, U0, U1);         \
        __syncthreads();                                                        \
        if ((sg) > 0 && (tid >> 3) == (sg) - 1) {                               \
            const int l_ = tid & 7;                                             \
            _Pragma("unroll")                                                   \
            for (int tt = 0; tt < T; ++tt) gbuf[tt] = pbuf[1 - (p)][tt][l_];    \
        }                                                                       \
        const int sl_ = tid >> 5, t_ = tid & 31;                                \
        float x_[21];                                                           \
        _Pragma("unroll")                                                       \
        for (int j = 0; j < 9; ++j) x_[j] = rbuf[p][sl_ * (32 * 9) + t_ * 9 + j]; \
        _Pragma("unroll")                                                       \
        for (int j = 0; j < 6; ++j) x_[9 + j] = vbuf[p][sl_ * (32 * 6) + t_ * 6 + j]; \
        _Pragma("unroll")                                                       \
        for (int j = 0; j < 6; ++j) x_[15 + j] = ubuf[p][sl_ * (32 * 6) + t_ * 6 + j]; \
        float4 g4_;                                                             \
        float* gp_ = (float*)&g4_;                                              \
        _Pragma("unroll")                                                       \
        for (int gi = 0; gi < 4; ++gi) {                                        \
            float acc_ = 0.f;                                                   \
            _Pragma("unroll")                                                   \
            for (int j = 0; j < 21; ++j) acc_ = fmaf(wi0[gi][j], x_[j], acc_);  \
            gp_[gi] = acc_;                                                     \
        }                                                                       \
        pbuf[p][t_][sl_] = g4_;                                                 \
    } while (0)

    ISSUE(0, Aa0, Aa1, Aa2, Av0, Av1, Au0, Au1);
    ISSUE(1, Ba0, Ba1, Ba2, Bv0, Bv1, Bu0, Bu1);

    for (int sg2 = 0; sg2 < 32; sg2 += 2) {
        BODY(sg2,     0, Aa0, Aa1, Aa2, Av0, Av1, Au0, Au1);
        BODY(sg2 + 1, 1, Ba0, Ba1, Ba2, Bv0, Bv1, Bu0, Bu1);
    }
    __syncthreads();
    if ((tid >> 3) == 31) {
        const int l_ = tid & 7;
#pragma unroll
        for (int tt = 0; tt < T; ++tt) gbuf[tt] = pbuf[1][tt][l_];
    }
#undef BODY
#undef ISSUE

    // ---------------- recurrence (all gates in registers) ----------------
    const int s = sBase + tid;
    float h[5] = {0.f, 0.f, 0.f, 0.f, 0.f};
    float c[5] = {0.f, 0.f, 0.f, 0.f, 0.f};
    float y0 = 0.f;

#pragma unroll
    for (int t = 0; t < T; ++t) {
        const float4 G = gbuf[t];
        float a0 = fmaf(whh[0][0], h[0], G.x);
        float a1 = fmaf(whh[0][1], h[0], G.y);
        float a2 = fmaf(whh[0][2], h[0], G.z);
        float a3 = fmaf(whh[0][3], h[0], G.w);
        {
            float ii = sigm(a0), ff = sigm(a1);
            float gg = tanh_fast(a2), oo = sigm(a3);
            c[0] = ff * c[0] + ii * gg;
            h[0] = oo * tanh_fast(c[0]);
        }
        float xin = h[0];
#pragma unroll
        for (int l = 1; l < 5; ++l) {
            float b0 = fmaf(wir[l - 1][0], xin, whh[l][0] * h[l]);
            float b1 = fmaf(wir[l - 1][1], xin, whh[l][1] * h[l]);
            float b2 = fmaf(wir[l - 1][2], xin, whh[l][2] * h[l]);
            float b3 = fmaf(wir[l - 1][3], xin, whh[l][3] * h[l]);
            float ii = sigm(b0), ff = sigm(b1);
            float gg = tanh_fast(b2), oo = sigm(b3);
            c[l] = ff * c[l] + ii * gg;
            h[l] = oo * tanh_fast(c[l]);
            xin = h[l];
        }
        if (t == 0) y0 = h[4];
    }

#pragma unroll
    for (int l = 0; l < 5; ++l) {
        out[(size_t)6 * k + (size_t)l * k + s] = h[l];
        out[(size_t)11 * k + (size_t)l * k + s] = c[l];
    }
    wsy[s] = y0;

    float ys = y0, yq = y0 * y0;
#pragma unroll
    for (int off = 32; off; off >>= 1) {
        ys += __shfl_down(ys, off);
        yq += __shfl_down(yq, off);
    }
    __shared__ float pS[4], pQ[4];
    const int wid = threadIdx.x >> 6, lane = threadIdx.x & 63;
    if (lane == 0) { pS[wid] = ys; pQ[wid] = yq; }
    __syncthreads();
    if (threadIdx.x == 0) {
        atomicAdd(&wsd[0], (double)(pS[0] + pS[1] + pS[2] + pS[3]));
        atomicAdd(&wsd[1], (double)(pQ[0] + pQ[1] + pQ[2] + pQ[3]));
    }
}

// ---------------- FC chain ---------------------------------------------------
__global__ __launch_bounds__(256)
void hist_kernel(const float* __restrict__ W1, const float* __restrict__ g1,
                 const float* __restrict__ b1, double* __restrict__ wsd,
                 const float* __restrict__ wsy, int k)
{
    __shared__ float sTau[32];
    __shared__ float sH[3 * NREG];
    __shared__ float sMy;
    const int tid = threadIdx.x;
    if (tid < 3 * NREG) sH[tid] = 0.f;
    if (tid < 32) {
        float my, vy, a, b, tau; int flip;
        bn1_params(W1, g1, b1, wsd, k, tid, my, vy, a, b, tau, flip);
        sTau[tid] = tau;
        if (tid == 0) sMy = my;
    }
    __syncthreads();
    const int stride = gridDim.x * 256;
    for (int s = blockIdx.x * 256 + tid; s < k; s += stride) {
        const float y = wsy[s];
        const float yc = y - sMy;
        int rgn = 0;
#pragma unroll
        for (int j = 0; j < 32; ++j) rgn += (y > sTau[j]) ? 1 : 0;
        atomicAdd(&sH[rgn], 1.0f);
        atomicAdd(&sH[NREG + rgn], yc);
        atomicAdd(&sH[2 * NREG + rgn], yc * yc);
    }
    __syncthreads();
    if (tid < 3 * NREG) atomicAdd(&wsd[2 + tid], (double)sH[tid]);
}

__global__ __launch_bounds__(256)
void tables_kernel(const float* __restrict__ W1, const float* __restrict__ g1,
                   const float* __restrict__ b1, const float* __restrict__ W2,
                   const float* __restrict__ g2, const float* __restrict__ b2,
                   const double* __restrict__ wsd, float* __restrict__ gPQ, int k)
{
    __shared__ float sA[32], sB[32], sTau[32];
    __shared__ int sRank[32], sFlip[32];
    __shared__ float sS0[NREG], sS1[NREG], sS2[NREG];
    __shared__ float sW2[1024];
    __shared__ float sSumY1[32];
    __shared__ float sM[1024];
    __shared__ float sI2[32], sM2v[32], sB2[32];
    const int tid = threadIdx.x;

    for (int i = tid; i < 1024; i += 256) sW2[i] = W2[i];
    if (tid < NREG) {
        sS0[tid] = (float)wsd[2 + tid];
        sS1[tid] = (float)wsd[2 + NREG + tid];
        sS2[tid] = (float)wsd[2 + 2 * NREG + tid];
    }
    if (tid < 32) {
        float my, vy, a, b, tau; int flip;
        bn1_params(W1, g1, b1, wsd, k, tid, my, vy, a, b, tau, flip);
        sA[tid] = a; sB[tid] = b; sTau[tid] = tau; sFlip[tid] = flip;
        sB2[tid] = b2[tid];
    }
    __syncthreads();
    if (tid < 32) {
        int rk = 0;
        float tj = sTau[tid];
#pragma unroll
        for (int l = 0; l < 32; ++l)
            rk += (sTau[l] < tj || (sTau[l] == tj && l < tid)) ? 1 : 0;
        sRank[tid] = rk;
    }
    __syncthreads();
    if (tid < 32) {
        const int rk = sRank[tid], fl = sFlip[tid];
        const float a = sA[tid], b = sB[tid];
        float acc = 0.f;
        for (int rg = 0; rg < NREG; ++rg) {
            float m = (((rk < rg) ? 1 : 0) != fl) ? 1.0f : NEGS;
            acc += m * (a * sS1[rg] + b * sS0[rg]);
        }
        sSumY1[tid] = acc;
    }
    for (int p = tid; p < 1024; p += 256) {
        const int j = p >> 5, l = p & 31;
        const int rj = sRank[j], fj = sFlip[j];
        const int rl = sRank[l], flp = sFlip[l];
        const float aj = sA[j], bj = sB[j], al = sA[l], bl = sB[l];
        const float caa = aj * al, cab = aj * bl + al * bj, cbb = bj * bl;
        float acc = 0.f;
        for (int rg = 0; rg < NREG; ++rg) {
            float mj = (((rj < rg) ? 1 : 0) != fj) ? 1.0f : NEGS;
            float ml = (((rl < rg) ? 1 : 0) != flp) ? 1.0f : NEGS;
            acc += mj * ml * (caa * sS2[rg] + cab * sS1[rg] + cbb * sS0[rg]);
        }
        sM[p] = acc;
    }
    __syncthreads();
    if (tid < 32) {
        const int i = tid;
        float s2 = 0.f, ss2 = 0.f;
#pragma unroll
        for (int j = 0; j < 32; ++j) {
            float wij = sW2[i * 32 + j];
            s2 = fmaf(wij, sSumY1[j], s2);
            float tj = 0.f;
#pragma unroll
            for (int l = 0; l < 32; ++l) tj = fmaf(sW2[i * 32 + l], sM[j * 32 + l], tj);
            ss2 = fmaf(wij, tj, ss2);
        }
        float m2 = s2 / k;
        float v2 = ss2 / k - m2 * m2;
        sM2v[i] = m2;
        sI2[i] = g2[i] * rsqrtf(v2 + EPS);
    }
    __syncthreads();
    for (int idx = tid; idx < NREG * 32; idx += 256) {
        const int rg = idx >> 5, i = idx & 31;
        float Ai = 0.f, Bi = 0.f;
#pragma unroll
        for (int j = 0; j < 32; ++j) {
            float m = (((sRank[j] < rg) ? 1 : 0) != sFlip[j]) ? 1.0f : NEGS;
            float w = sW2[i * 32 + j] * m;
            Ai = fmaf(w, sA[j], Ai);
            Bi = fmaf(w, sB[j], Bi);
        }
        gPQ[idx] = sI2[i] * Ai;
        gPQ[NREG * 32 + idx] = sI2[i] * (Bi - sM2v[i]) + sB2[i];
    }
}

__global__ __launch_bounds__(256)
void final_kernel(const float* __restrict__ W1, const float* __restrict__ g1,
                  const float* __restrict__ b1, const float* __restrict__ W3,
                  const double* __restrict__ wsd, const float* __restrict__ wsy,
                  const float* __restrict__ gPQ, float* __restrict__ out, int k)
{
    __shared__ float sTau[32], sW3[192], sMy;
    __shared__ float sP[NREG][33], sQ[NREG][33];
    const int tid = threadIdx.x;
    for (int idx = tid; idx < NREG * 32; idx += 256) {
        const int rg = idx >> 5, i = idx & 31;
        sP[rg][i] = gPQ[idx];
        sQ[rg][i] = gPQ[NREG * 32 + idx];
    }
    if (tid < 192) sW3[tid] = W3[tid];
    if (tid < 32) {
        float my, vy, a, b, tau; int flip;
        bn1_params(W1, g1, b1, wsd, k, tid, my, vy, a, b, tau, flip);
        sTau[tid] = tau;
        if (tid == 0) sMy = my;
    }
    __syncthreads();
    const int s = blockIdx.x * 256 + tid;
    const float y = wsy[s];
    const float yc = y - sMy;
    int rgn = 0;
#pragma unroll
    for (int j = 0; j < 32; ++j) rgn += (y > sTau[j]) ? 1 : 0;
    float dv[6] = {0.f, 0.f, 0.f, 0.f, 0.f, 0.f};
#pragma unroll
    for (int i = 0; i < 32; ++i) {
        float y2 = lrelu(fmaf(sP[rgn][i], yc, sQ[rgn][i]));
#pragma unroll
        for (int m = 0; m < 6; ++m) dv[m] = fmaf(sW3[m * 32 + i], y2, dv[m]);
    }
#pragma unroll
    for (int m = 0; m < 6; ++m) out[(size_t)s * 6 + m] = dv[m];
}

extern "C" void kernel_launch(void* const* d_in, const int* in_sizes, int n_in,
                              void* d_out, int out_size, void* d_ws, size_t ws_size,
                              hipStream_t stream)
{
    const float* r    = (const float*)d_in[0];
    const float* v    = (const float*)d_in[1];
    const float* u    = (const float*)d_in[2];
    const float* wih0 = (const float*)d_in[3];
    const float* wihr = (const float*)d_in[4];
    const float* whhp = (const float*)d_in[5];
    const float* W1   = (const float*)d_in[6];
    const float* g1v  = (const float*)d_in[7];
    const float* b1v  = (const float*)d_in[8];
    const float* W2   = (const float*)d_in[9];
    const float* g2v  = (const float*)d_in[10];
    const float* b2v  = (const float*)d_in[11];
    const float* W3   = (const float*)d_in[12];

    const int k = in_sizes[0] / (T * 9);   // 65536
    float* out = (float*)d_out;
    double* wsd = (double*)d_ws;
    float* wsy = (float*)((char*)d_ws + 1024);
    float* gPQ = (float*)((char*)d_ws + 1024 + (size_t)k * 4);

    hipMemsetAsync(d_ws, 0, 1024, stream);

    const int blocks = k / 256;
    fused_kernel<<<blocks, 256, 0, stream>>>(r, v, u, wih0, wihr, whhp,
                                             out, wsd, wsy, k);
    hist_kernel<<<64, 256, 0, stream>>>(W1, g1v, b1v, wsd, wsy, k);
    tables_kernel<<<1, 256, 0, stream>>>(W1, g1v, b1v, W2, g2v, b2v, wsd, gPQ, k);
    final_kernel<<<blocks, 256, 0, stream>>>(W1, g1v, b1v, W3, wsd, wsy, gPQ, out, k);
}